// Round 3
// baseline (504.948 us; speedup 1.0000x reference)
//
#include <hip/hip_runtime.h>

#define HH 512
#define WW 512
#define SS (HH * WW)          // elements per plane (2^18)
#define P16N (16 * SS)        // 16 planes (2^22)
#define PADW 576              // skewed LDS row: addr(j) = j + (j>>3)
#define PADW2 544             // tighter skew: addr(j) = j + (j>>4) (<=2-way, free)

constexpr float FINF = 3.402823466e38f;

__device__ __forceinline__ int swz(int j)  { return j + (j >> 3); }
__device__ __forceinline__ int swz2(int j) { return j + (j >> 4); }

__device__ __forceinline__ float gray1(float r, float g, float b) {
    return 0.299f * r + 0.587f * g + 0.114f * b;
}

// inverse of small integer c in [R+1, 2R+1] without v_div (cmp+cndmask chain)
template <int R>
__device__ __forceinline__ float invsmall(int c) {
    float r = 1.f / (float)(2 * R + 1);
    #pragma unroll
    for (int v = R + 1; v < 2 * R + 1; ++v)
        if (c == v) r = 1.f / (float)v;      // compile-time constants
    return r;
}

// ---------------- grad (gray fused, both dirs, 4 px/thread) ----------------
__global__ __launch_bounds__(256) void grad_both(const float* __restrict__ rgb,
                                                 float* __restrict__ dst,
                                                 int gxp0, int gyp0, int dirsel) {
    int sp = blockIdx.x * 256 + threadIdx.x;
    int idx = sp << 2;                             // [0, P16N)
    int img = idx >> 18;
    int pix = idx & (SS - 1);
    int i = pix >> 9, j0 = pix & (WW - 1);
    const float* p0 = rgb + (size_t)img * 3 * SS + pix;

    float4 r = *(const float4*)p0;
    float4 g = *(const float4*)(p0 + SS);
    float4 b = *(const float4*)(p0 + 2 * SS);
    float4 gy4 = make_float4(gray1(r.x, g.x, b.x), gray1(r.y, g.y, b.y),
                             gray1(r.z, g.z, b.z), gray1(r.w, g.w, b.w));
    if (dirsel != 1) {
        float grs = 0.f;
        if (j0 + 4 < WW) grs = gray1(p0[4], p0[SS + 4], p0[2 * SS + 4]);
        float4 gx = make_float4(gy4.x - gy4.y, gy4.y - gy4.z, gy4.z - gy4.w, gy4.w - grs);
        *(float4*)(dst + (size_t)(gxp0 + img) * SS + pix) = gx;
    }
    if (dirsel != 0) {
        float4 gd = make_float4(0.f, 0.f, 0.f, 0.f);
        if (i < HH - 1) {
            float4 r2 = *(const float4*)(p0 + WW);
            float4 g2 = *(const float4*)(p0 + SS + WW);
            float4 b2 = *(const float4*)(p0 + 2 * SS + WW);
            gd = make_float4(gray1(r2.x, g2.x, b2.x), gray1(r2.y, g2.y, b2.y),
                             gray1(r2.z, g2.z, b2.z), gray1(r2.w, g2.w, b2.w));
        }
        float4 gy = make_float4(gy4.x - gd.x, gy4.y - gd.y, gy4.z - gd.z, gy4.w - gd.w);
        *(float4*)(dst + (size_t)(gyp0 + img) * SS + pix) = gy;
    }
}

// ---------------- dual max+min pool (column-first, skewed LDS) ----------------
// Single ring buffer b[W]; out-of-range rows excluded by block-uniform masking.
// Vertical max -> LDS, vertical min -> regs; horizontal max -> dmax; reload;
// horizontal min -> dmin. TH=16: 36864 B LDS -> 4 blocks/CU.
template <bool PREABS, int R, int TH>
__global__ __launch_bounds__(256, 4) void dual_pool(const float* __restrict__ src,
                                                    float* __restrict__ dmax,
                                                    float* __restrict__ dmin) {
    constexpr int TILES = HH / TH;
    constexpr int W = 2 * R + 1;
    constexpr int NS = (TH * 64) / 256;
    __shared__ float lbuf[TH * PADW];

    const int plane = blockIdx.x / TILES;
    const int tile  = blockIdx.x % TILES;
    const int i0    = tile * TH;
    const size_t pbase = (size_t)plane * SS;
    const float* sp = src + pbase;
    const int t = threadIdx.x;
    const int ca = swz(2 * t);                     // ca+1 == swz(2t+1)

    float2 b[W];
    float2 keepmn[TH];
    auto ld = [&](int gi, float2& v) {
        float2 u = ((const float2*)(sp + (size_t)gi * WW))[t];
        if (PREABS) { u.x = fabsf(u.x); u.y = fabsf(u.y); }
        v = u;
    };
    #pragma unroll
    for (int k = 0; k < W; ++k)
        if ((unsigned)(i0 - R + k) < (unsigned)HH) ld(i0 - R + k, b[k]);
    #pragma unroll
    for (int oi = 0; oi < TH; ++oi) {
        if (oi > 0) {
            if ((unsigned)(i0 + oi + R) < (unsigned)HH) ld(i0 + oi + R, b[(oi - 1) % W]);
        }
        float2 mx = make_float2(-FINF, -FINF), mn = make_float2(FINF, FINF);
        #pragma unroll
        for (int k = 0; k < W; ++k) {
            int ro = k - R + ((oi > k) ? W : 0);   // compile-time except i0
            if ((unsigned)(i0 + ro) < (unsigned)HH) {   // block-uniform branch
                mx.x = fmaxf(mx.x, b[k].x); mx.y = fmaxf(mx.y, b[k].y);
                mn.x = fminf(mn.x, b[k].x); mn.y = fminf(mn.y, b[k].y);
            }
        }
        lbuf[oi * PADW + ca] = mx.x; lbuf[oi * PADW + ca + 1] = mx.y;
        keepmn[oi] = mn;
    }
    __syncthreads();

    // horizontal max -> dmax
    #pragma unroll
    for (int si = 0; si < NS; ++si) {
        int s = si * 256 + t;
        int rr = s >> 6, j0 = (s & 63) << 3;
        const float* rx = &lbuf[rr * PADW];
        float vx[2 * R + 8];
        #pragma unroll
        for (int k = 0; k < 2 * R + 8; ++k) {
            int jj = j0 - R + k;
            bool ok = (unsigned)jj < (unsigned)WW;
            int jc = swz(min(max(jj, 0), WW - 1));
            vx[k] = ok ? rx[jc] : -FINF;
        }
        float ox[8];
        #pragma unroll
        for (int d = 0; d < 8; ++d) {
            float mx = vx[d];
            #pragma unroll
            for (int k = 1; k <= 2 * R; ++k) mx = fmaxf(mx, vx[d + k]);
            ox[d] = mx;
        }
        size_t o = pbase + (size_t)(i0 + rr) * WW + j0;
        ((float4*)&dmax[o])[0] = make_float4(ox[0], ox[1], ox[2], ox[3]);
        ((float4*)&dmax[o])[1] = make_float4(ox[4], ox[5], ox[6], ox[7]);
    }
    __syncthreads();

    #pragma unroll
    for (int oi = 0; oi < TH; ++oi) {
        lbuf[oi * PADW + ca] = keepmn[oi].x;
        lbuf[oi * PADW + ca + 1] = keepmn[oi].y;
    }
    __syncthreads();

    // horizontal min -> dmin
    #pragma unroll
    for (int si = 0; si < NS; ++si) {
        int s = si * 256 + t;
        int rr = s >> 6, j0 = (s & 63) << 3;
        const float* rn = &lbuf[rr * PADW];
        float vn[2 * R + 8];
        #pragma unroll
        for (int k = 0; k < 2 * R + 8; ++k) {
            int jj = j0 - R + k;
            bool ok = (unsigned)jj < (unsigned)WW;
            int jc = swz(min(max(jj, 0), WW - 1));
            vn[k] = ok ? rn[jc] : FINF;
        }
        float on[8];
        #pragma unroll
        for (int d = 0; d < 8; ++d) {
            float mn = vn[d];
            #pragma unroll
            for (int k = 1; k <= 2 * R; ++k) mn = fminf(mn, vn[d + k]);
            on[d] = mn;
        }
        size_t o = pbase + (size_t)(i0 + rr) * WW + j0;
        ((float4*)&dmin[o])[0] = make_float4(on[0], on[1], on[2], on[3]);
        ((float4*)&dmin[o])[1] = make_float4(on[4], on[5], on[6], on[7]);
    }
}

// ---------------- dual-input avg pool + gn1 epilogue (EPI=1) ----------------
// out = (|e1|*chcw - racc2)/(|racc1 - racc2| + 1e-4*chcw)    [division-free form]
// Phase-split over ONE LDS buffer: s1 horizontal sums held in regs (keep1).
template <int R, int EPI, int TH>
__global__ __launch_bounds__(256, 4) void davg_pool(const float* __restrict__ s1,
                                                    const float* __restrict__ s2,
                                                    const float* __restrict__ e1,
                                                    const float* __restrict__ e2,
                                                    float* __restrict__ dst) {
    constexpr int TILES = HH / TH;
    constexpr int NS = (TH * 64) / 256;
    __shared__ float lbuf[TH * PADW];
    const int plane = blockIdx.x / TILES;
    const int tile  = blockIdx.x % TILES;
    const int i0    = tile * TH;
    const size_t pbase = (size_t)plane * SS;
    const int t = threadIdx.x;
    const int ca = swz(2 * t);

    auto vert = [&](const float* sp) {
        auto ld = [&](int gi) -> float2 {
            if ((unsigned)gi < (unsigned)HH) return ((const float2*)(sp + (size_t)gi * WW))[t];
            return make_float2(0.f, 0.f);
        };
        float2 acc = make_float2(0.f, 0.f);
        #pragma unroll
        for (int k = -R; k <= R; ++k) { float2 v = ld(i0 + k); acc.x += v.x; acc.y += v.y; }
        lbuf[ca] = acc.x; lbuf[ca + 1] = acc.y;
        #pragma unroll
        for (int oi = 1; oi < TH; ++oi) {
            float2 a = ld(i0 + oi + R), s = ld(i0 + oi - R - 1);
            acc.x += a.x - s.x; acc.y += a.y - s.y;
            lbuf[oi * PADW + ca] = acc.x; lbuf[oi * PADW + ca + 1] = acc.y;
        }
    };

    float keep1[NS * 8];                           // raw horizontal sums of s1

    // ---- phase A: s1 ----
    vert(s1 + pbase);
    __syncthreads();
    #pragma unroll
    for (int si = 0; si < NS; ++si) {
        int s = si * 256 + t;
        int rr = s >> 6, j0 = (s & 63) << 3;
        const float* row = &lbuf[rr * PADW];
        int lo = max(j0 - R, 0), hi = min(j0 + R, WW - 1);
        float racc = 0.f;
        for (int jj = lo; jj <= hi; ++jj) racc += row[swz(jj)];
        #pragma unroll
        for (int d = 0; d < 8; ++d) {
            if (d > 0) {
                int add = j0 + d + R, sub = j0 + d - R - 1;
                if (add < WW) racc += row[swz(add)];
                if (sub >= 0) racc -= row[swz(sub)];
            }
            keep1[si * 8 + d] = racc;
        }
    }
    __syncthreads();

    // ---- phase B: s2 + epilogue ----
    vert(s2 + pbase);
    __syncthreads();
    #pragma unroll
    for (int si = 0; si < NS; ++si) {
        int s = si * 256 + t;
        int rr = s >> 6, j0 = (s & 63) << 3;
        int i = i0 + rr;
        int ch = min(i + R, HH - 1) - max(i - R, 0) + 1;
        const float* row = &lbuf[rr * PADW];
        size_t rowbase = pbase + (size_t)i * WW + j0;

        float e1v[8], e2v[8];
        {
            float4 a0 = ((const float4*)(e1 + rowbase))[0];
            float4 a1q = ((const float4*)(e1 + rowbase))[1];
            e1v[0]=a0.x; e1v[1]=a0.y; e1v[2]=a0.z; e1v[3]=a0.w;
            e1v[4]=a1q.x; e1v[5]=a1q.y; e1v[6]=a1q.z; e1v[7]=a1q.w;
        }
        if (EPI == 2) {
            float4 b0 = ((const float4*)(e2 + rowbase))[0];
            float4 b1q = ((const float4*)(e2 + rowbase))[1];
            e2v[0]=b0.x; e2v[1]=b0.y; e2v[2]=b0.z; e2v[3]=b0.w;
            e2v[4]=b1q.x; e2v[5]=b1q.y; e2v[6]=b1q.z; e2v[7]=b1q.w;
        }

        int lo = max(j0 - R, 0), hi = min(j0 + R, WW - 1);
        float racc2 = 0.f;
        for (int jj = lo; jj <= hi; ++jj) racc2 += row[swz(jj)];
        float ov[8];
        #pragma unroll
        for (int d = 0; d < 8; ++d) {
            if (d > 0) {
                int add = j0 + d + R, sub = j0 + d - R - 1;
                if (add < WW) racc2 += row[swz(add)];
                if (sub >= 0) racc2 -= row[swz(sub)];
            }
            int j = j0 + d;
            int cw = min(j + R, WW - 1) - max(j - R, 0) + 1;
            float chcw = (float)(ch * cw);
            float r1 = keep1[si * 8 + d];
            float den = fabsf(r1 - racc2) + 1e-4f * chcw;
            if (EPI == 1) {
                ov[d] = (fabsf(e1v[d]) * chcw - racc2) / den;
            } else {
                ov[d] = ((e1v[d] * chcw - racc2) / den + 0.01f) * e2v[d];
            }
        }
        float4* d4 = (float4*)&dst[rowbase];
        d4[0] = make_float4(ov[0], ov[1], ov[2], ov[3]);
        d4[1] = make_float4(ov[4], ov[5], ov[6], ov[7]);
    }
}

// ---------------- fused go + dual max/min pool ----------------
// go = |avg5x5(g)| computed on the fly (streaming colsum rows through a 2-slot
// LDS rotation, 1 barrier/row), fed into the vertical max/min ring (R=3) and
// written out once. Outputs: dgo=go, dmax=max7(go), dmin=min7(go).
// LDS: (TH+2) rows at PADW2 -> 39168 B -> 4 blocks/CU.
template <int TH>
__global__ __launch_bounds__(256, 4) void go_dual(const float* __restrict__ gsrc,
                                                  float* __restrict__ dgo,
                                                  float* __restrict__ dmax,
                                                  float* __restrict__ dmin) {
    constexpr int TILES = HH / TH;
    constexpr int R = 3, W = 2 * R + 1, R2 = 2;
    constexpr int NROW = TH + 2 * R;               // go rows needed
    constexpr int NS = (TH * 64) / 256;
    __shared__ float lbuf[(TH + 2) * PADW2];       // rows 0..TH-1: vmax; TH,TH+1: colsum slots

    const int plane = blockIdx.x / TILES;
    const int tile  = blockIdx.x % TILES;
    const int i0    = tile * TH;
    const size_t pbase = (size_t)plane * SS;
    const float* sp = gsrc + pbase;
    const int t = threadIdx.x;
    const int c0 = 2 * t;
    const int ca = swz2(c0);                       // ca+1 == swz2(c0+1)

    const float invcw0 = invsmall<R2>(min(c0 + R2, WW - 1) - max(c0 - R2, 0) + 1);
    const float invcw1 = invsmall<R2>(min(c0 + 1 + R2, WW - 1) - max(c0 + 1 - R2, 0) + 1);

    auto ld = [&](int gi) -> float2 {
        return ((const float2*)(sp + (size_t)gi * WW))[t];
    };

    const int rlo = i0 - R;                        // first go row (may be <0)
    float2 cs = make_float2(0.f, 0.f);             // vertical 5-sum of g at own cols
    #pragma unroll
    for (int k = -R2; k <= R2; ++k) {
        int rr = rlo + k;
        if ((unsigned)rr < (unsigned)HH) { float2 v = ld(rr); cs.x += v.x; cs.y += v.y; }
    }

    float2 ring[W];
    float2 keepmn[TH];

    #pragma unroll
    for (int s = 0; s < NROW; ++s) {
        const int r = rlo + s;                     // current go row
        if (s > 0) {                               // advance colsum
            int ra = r + R2, rs = r - R2 - 1;
            if ((unsigned)ra < (unsigned)HH) { float2 v = ld(ra); cs.x += v.x; cs.y += v.y; }
            if ((unsigned)rs < (unsigned)HH) { float2 v = ld(rs); cs.x -= v.x; cs.y -= v.y; }
        }
        float* srow = &lbuf[(TH + (s & 1)) * PADW2];
        srow[ca] = cs.x; srow[ca + 1] = cs.y;
        __syncthreads();
        float2 go2 = make_float2(0.f, 0.f);
        if ((unsigned)r < (unsigned)HH) {          // block-uniform
            int ch = min(r + R2, HH - 1) - max(r - R2, 0) + 1;
            float invch = invsmall<R2>(ch);
            float h[2 * R2 + 2];
            #pragma unroll
            for (int k = 0; k < 2 * R2 + 2; ++k) {
                int c = c0 - R2 + k;
                h[k] = ((unsigned)c < (unsigned)WW) ? srow[swz2(c)] : 0.f;
            }
            float s0 = 0.f, s1v = 0.f;
            #pragma unroll
            for (int k = 0; k < 2 * R2 + 1; ++k) { s0 += h[k]; s1v += h[k + 1]; }
            go2.x = fabsf(s0 * (invch * invcw0));
            go2.y = fabsf(s1v * (invch * invcw1));
            if ((unsigned)(r - i0) < (unsigned)TH)
                *(float2*)(dgo + pbase + (size_t)r * WW + c0) = go2;
        }
        ring[s % W] = go2;                         // invalid rows hold {0,0}, masked at emit
        if (s >= 2 * R) {                          // emit output row oi = s - 2R
            const int oi = s - 2 * R;
            float2 mx = make_float2(-FINF, -FINF), mn = make_float2(FINF, FINF);
            #pragma unroll
            for (int k = 0; k < W; ++k) {
                int rk = r - k;
                if ((unsigned)rk < (unsigned)HH) {     // block-uniform
                    float2 v = ring[(s - k) % W];      // compile-time modulo (unrolled)
                    mx.x = fmaxf(mx.x, v.x); mx.y = fmaxf(mx.y, v.y);
                    mn.x = fminf(mn.x, v.x); mn.y = fminf(mn.y, v.y);
                }
            }
            lbuf[oi * PADW2 + ca] = mx.x; lbuf[oi * PADW2 + ca + 1] = mx.y;
            keepmn[oi] = mn;
        }
        // 2-slot rotation: next write to this slot is 2 barriers away -> safe
    }
    __syncthreads();

    // horizontal max -> dmax
    #pragma unroll
    for (int si = 0; si < NS; ++si) {
        int s = si * 256 + t;
        int rr = s >> 6, j0 = (s & 63) << 3;
        const float* rx = &lbuf[rr * PADW2];
        float vx[2 * R + 8];
        #pragma unroll
        for (int k = 0; k < 2 * R + 8; ++k) {
            int jj = j0 - R + k;
            bool ok = (unsigned)jj < (unsigned)WW;
            int jc = swz2(min(max(jj, 0), WW - 1));
            vx[k] = ok ? rx[jc] : -FINF;
        }
        float ox[8];
        #pragma unroll
        for (int d = 0; d < 8; ++d) {
            float mx = vx[d];
            #pragma unroll
            for (int k = 1; k <= 2 * R; ++k) mx = fmaxf(mx, vx[d + k]);
            ox[d] = mx;
        }
        size_t o = pbase + (size_t)(i0 + rr) * WW + j0;
        ((float4*)&dmax[o])[0] = make_float4(ox[0], ox[1], ox[2], ox[3]);
        ((float4*)&dmax[o])[1] = make_float4(ox[4], ox[5], ox[6], ox[7]);
    }
    __syncthreads();

    #pragma unroll
    for (int oi = 0; oi < TH; ++oi) {
        lbuf[oi * PADW2 + ca] = keepmn[oi].x;
        lbuf[oi * PADW2 + ca + 1] = keepmn[oi].y;
    }
    __syncthreads();

    // horizontal min -> dmin
    #pragma unroll
    for (int si = 0; si < NS; ++si) {
        int s = si * 256 + t;
        int rr = s >> 6, j0 = (s & 63) << 3;
        const float* rn = &lbuf[rr * PADW2];
        float vn[2 * R + 8];
        #pragma unroll
        for (int k = 0; k < 2 * R + 8; ++k) {
            int jj = j0 - R + k;
            bool ok = (unsigned)jj < (unsigned)WW;
            int jc = swz2(min(max(jj, 0), WW - 1));
            vn[k] = ok ? rn[jc] : FINF;
        }
        float on[8];
        #pragma unroll
        for (int d = 0; d < 8; ++d) {
            float mn = vn[d];
            #pragma unroll
            for (int k = 1; k <= 2 * R; ++k) mn = fminf(mn, vn[d + k]);
            on[d] = mn;
        }
        size_t o = pbase + (size_t)(i0 + rr) * WW + j0;
        ((float4*)&dmin[o])[0] = make_float4(on[0], on[1], on[2], on[3]);
        ((float4*)&dmin[o])[1] = make_float4(on[4], on[5], on[6], on[7]);
    }
}

// ---------------- final: dual avg + map + paired reduction ----------------
// Each block handles planes (pR, pR+16) = (R, L) for one tile. Computes
// mapR, mapL in registers (no map write), accumulates
// sum mapR*exp(-10*(mapR+mapL)) -> one partial per block.
// map = ((e1*chcw - racc2)/(|racc1-racc2| + 1e-4*chcw) + 0.01) * e2
template <int R, int TH>
__global__ __launch_bounds__(256, 4) void davg_final(const float* __restrict__ s1,
                                                     const float* __restrict__ s2,
                                                     const float* __restrict__ e1,
                                                     const float* __restrict__ e2,
                                                     float* __restrict__ partials) {
    constexpr int TILES = HH / TH;
    constexpr int NS = (TH * 64) / 256;
    __shared__ float lbuf[TH * PADW];
    __shared__ float red[4];
    const int pairidx = blockIdx.x / TILES;
    const int tile    = blockIdx.x % TILES;
    const int i0      = tile * TH;
    const int planeR  = pairidx + ((pairidx >> 4) << 4);   // 0..15 -> 0..15; 16..31 -> 32..47
    const int t = threadIdx.x;
    const int ca = swz(2 * t);

    float mapR[NS * 8];
    float acc = 0.f;

    #pragma unroll
    for (int half = 0; half < 2; ++half) {
        const size_t pbase = (size_t)(planeR + half * 16) * SS;

        auto vert = [&](const float* sp) {
            auto ld = [&](int gi) -> float2 {
                if ((unsigned)gi < (unsigned)HH) return ((const float2*)(sp + (size_t)gi * WW))[t];
                return make_float2(0.f, 0.f);
            };
            float2 a = make_float2(0.f, 0.f);
            #pragma unroll
            for (int k = -R; k <= R; ++k) { float2 v = ld(i0 + k); a.x += v.x; a.y += v.y; }
            lbuf[ca] = a.x; lbuf[ca + 1] = a.y;
            #pragma unroll
            for (int oi = 1; oi < TH; ++oi) {
                float2 p = ld(i0 + oi + R), q = ld(i0 + oi - R - 1);
                a.x += p.x - q.x; a.y += p.y - q.y;
                lbuf[oi * PADW + ca] = a.x; lbuf[oi * PADW + ca + 1] = a.y;
            }
        };

        float keep1[NS * 8];

        // phase A: s1 (max7)
        vert(s1 + pbase);
        __syncthreads();
        #pragma unroll
        for (int si = 0; si < NS; ++si) {
            int s = si * 256 + t;
            int rr = s >> 6, j0 = (s & 63) << 3;
            const float* row = &lbuf[rr * PADW];
            int lo = max(j0 - R, 0), hi = min(j0 + R, WW - 1);
            float racc = 0.f;
            for (int jj = lo; jj <= hi; ++jj) racc += row[swz(jj)];
            #pragma unroll
            for (int d = 0; d < 8; ++d) {
                if (d > 0) {
                    int add = j0 + d + R, sub = j0 + d - R - 1;
                    if (add < WW) racc += row[swz(add)];
                    if (sub >= 0) racc -= row[swz(sub)];
                }
                keep1[si * 8 + d] = racc;
            }
        }
        __syncthreads();

        // phase B: s2 (min7) + epilogue
        vert(s2 + pbase);
        __syncthreads();
        #pragma unroll
        for (int si = 0; si < NS; ++si) {
            int s = si * 256 + t;
            int rr = s >> 6, j0 = (s & 63) << 3;
            int i = i0 + rr;
            int ch = min(i + R, HH - 1) - max(i - R, 0) + 1;
            const float* row = &lbuf[rr * PADW];
            size_t rowbase = pbase + (size_t)i * WW + j0;

            float e1v[8], e2v[8];
            {
                float4 a0 = ((const float4*)(e1 + rowbase))[0];
                float4 a1q = ((const float4*)(e1 + rowbase))[1];
                e1v[0]=a0.x; e1v[1]=a0.y; e1v[2]=a0.z; e1v[3]=a0.w;
                e1v[4]=a1q.x; e1v[5]=a1q.y; e1v[6]=a1q.z; e1v[7]=a1q.w;
                float4 b0 = ((const float4*)(e2 + rowbase))[0];
                float4 b1q = ((const float4*)(e2 + rowbase))[1];
                e2v[0]=b0.x; e2v[1]=b0.y; e2v[2]=b0.z; e2v[3]=b0.w;
                e2v[4]=b1q.x; e2v[5]=b1q.y; e2v[6]=b1q.z; e2v[7]=b1q.w;
            }

            int lo = max(j0 - R, 0), hi = min(j0 + R, WW - 1);
            float racc2 = 0.f;
            for (int jj = lo; jj <= hi; ++jj) racc2 += row[swz(jj)];
            #pragma unroll
            for (int d = 0; d < 8; ++d) {
                if (d > 0) {
                    int add = j0 + d + R, sub = j0 + d - R - 1;
                    if (add < WW) racc2 += row[swz(add)];
                    if (sub >= 0) racc2 -= row[swz(sub)];
                }
                int j = j0 + d;
                int cw = min(j + R, WW - 1) - max(j - R, 0) + 1;
                float chcw = (float)(ch * cw);
                float r1 = keep1[si * 8 + d];
                float den = fabsf(r1 - racc2) + 1e-4f * chcw;
                float mp = ((e1v[d] * chcw - racc2) / den + 0.01f) * e2v[d];
                if (half == 0) {
                    mapR[si * 8 + d] = mp;
                } else {
                    float mr = mapR[si * 8 + d];
                    acc += mr * expf(-10.f * (mr + mp));
                }
            }
        }
        __syncthreads();                           // before lbuf reuse / end
    }

    #pragma unroll
    for (int off = 32; off; off >>= 1) acc += __shfl_down(acc, off);
    int lane = t & 63, wv = t >> 6;
    if (lane == 0) red[wv] = acc;
    __syncthreads();
    if (t == 0) partials[blockIdx.x] = red[0] + red[1] + red[2] + red[3];
}

// ---------------- final partial reduction ----------------
__global__ __launch_bounds__(256) void reduce2(const float* __restrict__ partials,
                                               float* __restrict__ out, float scale, int n) {
    float v = 0.f;
    for (int i = threadIdx.x; i < n; i += 256) v += partials[i];
    for (int off = 32; off; off >>= 1) v += __shfl_down(v, off);
    __shared__ float lds[4];
    int lane = threadIdx.x & 63, wv = threadIdx.x >> 6;
    if (lane == 0) lds[wv] = v;
    __syncthreads();
    if (threadIdx.x == 0) atomicAdd(out, (lds[0] + lds[1] + lds[2] + lds[3]) * scale);
}

// ---------------- host orchestration ----------------

extern "C" void kernel_launch(void* const* d_in, const int* in_sizes, int n_in,
                              void* d_out, int out_size, void* d_ws, size_t ws_size,
                              hipStream_t stream) {
    const float* Rrgb = (const float*)d_in[0];
    const float* Lrgb = (const float*)d_in[1];
    float* out = (float*)d_out;
    float* w = (float*)d_ws;
    const float scale = 1.f / (float)P16N;
    const int gradblk = (P16N / 4 + 255) / 256;

    hipMemsetAsync(out, 0, sizeof(float) * (size_t)out_size, stream);

    const size_t stack64 = (size_t)64 * SS;
    const size_t stack32 = (size_t)32 * SS;

    if (ws_size >= (5 * stack64 + 4096) * sizeof(float)) {
        // single pass: 5 buffers of 64 planes [0..16)=Rgx [16..32)=Lgx [32..48)=Rgy [48..64)=Lgy
        float* G = w;
        float* A = G + stack64;
        float* B = A + stack64;
        float* C = B + stack64;
        float* D = C + stack64;
        float* partials = D + stack64;
        grad_both<<<gradblk, 256, 0, stream>>>(Rrgb, G, 0, 32, 2);
        grad_both<<<gradblk, 256, 0, stream>>>(Lrgb, G, 16, 48, 2);
        int gp = 64 * (HH / 16);
        dual_pool<true, 4, 16><<<gp, 256, 0, stream>>>(G, A, B);      // A=max9|g|, B=min9|g|
        davg_pool<8, 1, 16><<<gp, 256, 0, stream>>>(A, B, G, nullptr, C); // C=gn1
        go_dual<16><<<gp, 256, 0, stream>>>(G, D, A, B);              // D=go, A=max7, B=min7
        int fp = 32 * (HH / 16);
        davg_final<3, 16><<<fp, 256, 0, stream>>>(A, B, D, C, partials);
        reduce2<<<1, 256, 0, stream>>>(partials, out, scale, fp);
    } else {
        // two passes: 5 buffers of 32 planes (168 MB), one direction at a time
        float* G = w;
        float* A = G + stack32;
        float* B = A + stack32;
        float* C = B + stack32;
        float* D = C + stack32;
        float* partials = D + stack32;
        for (int dir = 0; dir < 2; ++dir) {
            grad_both<<<gradblk, 256, 0, stream>>>(Rrgb, G, 0, 0, dir);
            grad_both<<<gradblk, 256, 0, stream>>>(Lrgb, G, 16, 16, dir);
            int gp = 32 * (HH / 16);
            dual_pool<true, 4, 16><<<gp, 256, 0, stream>>>(G, A, B);
            davg_pool<8, 1, 16><<<gp, 256, 0, stream>>>(A, B, G, nullptr, C);
            go_dual<16><<<gp, 256, 0, stream>>>(G, D, A, B);
            int fp = 16 * (HH / 16);
            davg_final<3, 16><<<fp, 256, 0, stream>>>(A, B, D, C, partials);
            reduce2<<<1, 256, 0, stream>>>(partials, out, scale, fp);
        }
    }
}

// Round 4
// 499.130 us; speedup vs baseline: 1.0117x; 1.0117x over previous
//
#include <hip/hip_runtime.h>

#define HH 512
#define WW 512
#define SS (HH * WW)          // elements per plane (2^18)
#define P16N (16 * SS)        // 16 planes (2^22)
#define PADW 576              // skewed LDS row: addr(j) = j + (j>>3)

constexpr float FINF = 3.402823466e38f;

__device__ __forceinline__ int swz(int j) { return j + (j >> 3); }

__device__ __forceinline__ float gray1(float r, float g, float b) {
    return 0.299f * r + 0.587f * g + 0.114f * b;
}

// inverse of small integer c in [R+1, 2R+1] without v_div (cmp+cndmask chain)
template <int R>
__device__ __forceinline__ float invsmall(int c) {
    float r = 1.f / (float)(2 * R + 1);
    #pragma unroll
    for (int v = R + 1; v < 2 * R + 1; ++v)
        if (c == v) r = 1.f / (float)v;      // compile-time constants
    return r;
}

// ---------------- grad (gray fused, both dirs, 4 px/thread) ----------------
__global__ __launch_bounds__(256) void grad_both(const float* __restrict__ rgb,
                                                 float* __restrict__ dst,
                                                 int gxp0, int gyp0, int dirsel) {
    int sp = blockIdx.x * 256 + threadIdx.x;
    int idx = sp << 2;                             // [0, P16N)
    int img = idx >> 18;
    int pix = idx & (SS - 1);
    int i = pix >> 9, j0 = pix & (WW - 1);
    const float* p0 = rgb + (size_t)img * 3 * SS + pix;

    float4 r = *(const float4*)p0;
    float4 g = *(const float4*)(p0 + SS);
    float4 b = *(const float4*)(p0 + 2 * SS);
    float4 gy4 = make_float4(gray1(r.x, g.x, b.x), gray1(r.y, g.y, b.y),
                             gray1(r.z, g.z, b.z), gray1(r.w, g.w, b.w));
    if (dirsel != 1) {
        float grs = 0.f;
        if (j0 + 4 < WW) grs = gray1(p0[4], p0[SS + 4], p0[2 * SS + 4]);
        float4 gx = make_float4(gy4.x - gy4.y, gy4.y - gy4.z, gy4.z - gy4.w, gy4.w - grs);
        *(float4*)(dst + (size_t)(gxp0 + img) * SS + pix) = gx;
    }
    if (dirsel != 0) {
        float4 gd = make_float4(0.f, 0.f, 0.f, 0.f);
        if (i < HH - 1) {
            float4 r2 = *(const float4*)(p0 + WW);
            float4 g2 = *(const float4*)(p0 + SS + WW);
            float4 b2 = *(const float4*)(p0 + 2 * SS + WW);
            gd = make_float4(gray1(r2.x, g2.x, b2.x), gray1(r2.y, g2.y, b2.y),
                             gray1(r2.z, g2.z, b2.z), gray1(r2.w, g2.w, b2.w));
        }
        float4 gy = make_float4(gy4.x - gd.x, gy4.y - gd.y, gy4.z - gd.z, gy4.w - gd.w);
        *(float4*)(dst + (size_t)(gyp0 + img) * SS + pix) = gy;
    }
}

// ---------------- dual max+min pool (column-first, skewed LDS) ----------------
// 512 threads: one column per thread. Single ring buffer rb[W]; out-of-range /
// stale rows excluded by EXACT wrap-counted validity mask (all compile-time).
// Vertical max -> LDS, vertical min -> regs; horizontal max -> dmax; reload;
// horizontal min -> dmin. LDS 36864 B -> 4 blocks/CU x 8 waves = 32 waves/CU.
template <bool PREABS, int R, int TH>
__global__ __launch_bounds__(512, 8) void dual_pool(const float* __restrict__ src,
                                                    float* __restrict__ dmax,
                                                    float* __restrict__ dmin) {
    constexpr int TILES = HH / TH;
    constexpr int W = 2 * R + 1;
    constexpr int NS = (TH * 64) / 512;
    __shared__ float lbuf[TH * PADW];

    const int plane = blockIdx.x / TILES;
    const int tile  = blockIdx.x % TILES;
    const int i0    = tile * TH;
    const size_t pbase = (size_t)plane * SS;
    const float* sp = src + pbase;
    const int t = threadIdx.x;                     // column 0..511
    const int ca = swz(t);

    float rb[W];
    float keepmn[TH];
    auto ld = [&](int gi) -> float {
        float u = sp[(size_t)gi * WW + t];
        return PREABS ? fabsf(u) : u;
    };
    #pragma unroll
    for (int k = 0; k < W; ++k)
        if ((unsigned)(i0 - R + k) < (unsigned)HH) rb[k] = ld(i0 - R + k);
    #pragma unroll
    for (int oi = 0; oi < TH; ++oi) {
        if (oi > 0) {
            if ((unsigned)(i0 + oi + R) < (unsigned)HH) rb[(oi - 1) % W] = ld(i0 + oi + R);
        }
        float mx = -FINF, mn = FINF;
        #pragma unroll
        for (int k = 0; k < W; ++k) {
            int wrap = (oi > k) ? ((oi - 1 - k) / W + 1) : 0;   // compile-time
            int ro = k - R + wrap * W;                          // exact row in slot k
            if ((unsigned)(i0 + ro) < (unsigned)HH) {           // block-uniform
                mx = fmaxf(mx, rb[k]); mn = fminf(mn, rb[k]);
            }
        }
        lbuf[oi * PADW + ca] = mx;
        keepmn[oi] = mn;
    }
    __syncthreads();

    // horizontal max -> dmax
    #pragma unroll
    for (int si = 0; si < NS; ++si) {
        int s = si * 512 + t;
        int rr = s >> 6, j0 = (s & 63) << 3;
        const float* rx = &lbuf[rr * PADW];
        float vx[2 * R + 8];
        #pragma unroll
        for (int k = 0; k < 2 * R + 8; ++k) {
            int jj = j0 - R + k;
            bool ok = (unsigned)jj < (unsigned)WW;
            int jc = swz(min(max(jj, 0), WW - 1));
            vx[k] = ok ? rx[jc] : -FINF;
        }
        float ox[8];
        #pragma unroll
        for (int d = 0; d < 8; ++d) {
            float mx = vx[d];
            #pragma unroll
            for (int k = 1; k <= 2 * R; ++k) mx = fmaxf(mx, vx[d + k]);
            ox[d] = mx;
        }
        size_t o = pbase + (size_t)(i0 + rr) * WW + j0;
        ((float4*)&dmax[o])[0] = make_float4(ox[0], ox[1], ox[2], ox[3]);
        ((float4*)&dmax[o])[1] = make_float4(ox[4], ox[5], ox[6], ox[7]);
    }
    __syncthreads();

    #pragma unroll
    for (int oi = 0; oi < TH; ++oi) lbuf[oi * PADW + ca] = keepmn[oi];
    __syncthreads();

    // horizontal min -> dmin
    #pragma unroll
    for (int si = 0; si < NS; ++si) {
        int s = si * 512 + t;
        int rr = s >> 6, j0 = (s & 63) << 3;
        const float* rn = &lbuf[rr * PADW];
        float vn[2 * R + 8];
        #pragma unroll
        for (int k = 0; k < 2 * R + 8; ++k) {
            int jj = j0 - R + k;
            bool ok = (unsigned)jj < (unsigned)WW;
            int jc = swz(min(max(jj, 0), WW - 1));
            vn[k] = ok ? rn[jc] : FINF;
        }
        float on[8];
        #pragma unroll
        for (int d = 0; d < 8; ++d) {
            float mn = vn[d];
            #pragma unroll
            for (int k = 1; k <= 2 * R; ++k) mn = fminf(mn, vn[d + k]);
            on[d] = mn;
        }
        size_t o = pbase + (size_t)(i0 + rr) * WW + j0;
        ((float4*)&dmin[o])[0] = make_float4(on[0], on[1], on[2], on[3]);
        ((float4*)&dmin[o])[1] = make_float4(on[4], on[5], on[6], on[7]);
    }
}

// ---------------- single avg pool (abs output), division-free, 512 thr ----------------
template <int R, int TH>
__global__ __launch_bounds__(512, 8) void avg_abs_pool(const float* __restrict__ src,
                                                       float* __restrict__ dst) {
    constexpr int TILES = HH / TH;
    constexpr int NS = (TH * 64) / 512;
    __shared__ float ls[TH * PADW];
    const int plane = blockIdx.x / TILES;
    const int tile  = blockIdx.x % TILES;
    const int i0    = tile * TH;
    const size_t pbase = (size_t)plane * SS;
    const float* sp = src + pbase;
    const int t = threadIdx.x;
    const int ca = swz(t);

    auto ld = [&](int gi) -> float {
        return ((unsigned)gi < (unsigned)HH) ? sp[(size_t)gi * WW + t] : 0.f;
    };
    float acc = 0.f;
    #pragma unroll
    for (int k = -R; k <= R; ++k) acc += ld(i0 + k);
    ls[ca] = acc;
    #pragma unroll
    for (int oi = 1; oi < TH; ++oi) {
        acc += ld(i0 + oi + R) - ld(i0 + oi - R - 1);
        ls[oi * PADW + ca] = acc;
    }
    __syncthreads();

    #pragma unroll
    for (int si = 0; si < NS; ++si) {
        int s = si * 512 + t;
        int rr = s >> 6, j0 = (s & 63) << 3;
        int i = i0 + rr;
        int ch = min(i + R, HH - 1) - max(i - R, 0) + 1;
        float invch = invsmall<R>(ch);
        const float* row = &ls[rr * PADW];
        int lo = max(j0 - R, 0), hi = min(j0 + R, WW - 1);
        float racc = 0.f;
        for (int jj = lo; jj <= hi; ++jj) racc += row[swz(jj)];
        float ov[8];
        #pragma unroll
        for (int d = 0; d < 8; ++d) {
            if (d > 0) {
                int add = j0 + d + R, sub = j0 + d - R - 1;
                if (add < WW) racc += row[swz(add)];
                if (sub >= 0) racc -= row[swz(sub)];
            }
            int j = j0 + d;
            int cw = min(j + R, WW - 1) - max(j - R, 0) + 1;
            ov[d] = fabsf(racc * (invch * invsmall<R>(cw)));
        }
        float4* d4 = (float4*)&dst[pbase + (size_t)i * WW + j0];
        d4[0] = make_float4(ov[0], ov[1], ov[2], ov[3]);
        d4[1] = make_float4(ov[4], ov[5], ov[6], ov[7]);
    }
}

// ---------------- dual-input avg pool + gn1 epilogue (EPI=1), 512 thr ----------------
// out = (|e1|*chcw - racc2)/(|racc1 - racc2| + 1e-4*chcw)    [division-free form]
// Phase-split over ONE LDS buffer: s1 horizontal sums held in regs (keep1).
template <int R, int EPI, int TH>
__global__ __launch_bounds__(512, 8) void davg_pool(const float* __restrict__ s1,
                                                    const float* __restrict__ s2,
                                                    const float* __restrict__ e1,
                                                    const float* __restrict__ e2,
                                                    float* __restrict__ dst) {
    constexpr int TILES = HH / TH;
    constexpr int NS = (TH * 64) / 512;
    __shared__ float lbuf[TH * PADW];
    const int plane = blockIdx.x / TILES;
    const int tile  = blockIdx.x % TILES;
    const int i0    = tile * TH;
    const size_t pbase = (size_t)plane * SS;
    const int t = threadIdx.x;
    const int ca = swz(t);

    auto vert = [&](const float* sp) {
        auto ld = [&](int gi) -> float {
            return ((unsigned)gi < (unsigned)HH) ? sp[(size_t)gi * WW + t] : 0.f;
        };
        float acc = 0.f;
        #pragma unroll
        for (int k = -R; k <= R; ++k) acc += ld(i0 + k);
        lbuf[ca] = acc;
        #pragma unroll
        for (int oi = 1; oi < TH; ++oi) {
            acc += ld(i0 + oi + R) - ld(i0 + oi - R - 1);
            lbuf[oi * PADW + ca] = acc;
        }
    };

    float keep1[NS * 8];                           // raw horizontal sums of s1

    // ---- phase A: s1 ----
    vert(s1 + pbase);
    __syncthreads();
    #pragma unroll
    for (int si = 0; si < NS; ++si) {
        int s = si * 512 + t;
        int rr = s >> 6, j0 = (s & 63) << 3;
        const float* row = &lbuf[rr * PADW];
        int lo = max(j0 - R, 0), hi = min(j0 + R, WW - 1);
        float racc = 0.f;
        for (int jj = lo; jj <= hi; ++jj) racc += row[swz(jj)];
        #pragma unroll
        for (int d = 0; d < 8; ++d) {
            if (d > 0) {
                int add = j0 + d + R, sub = j0 + d - R - 1;
                if (add < WW) racc += row[swz(add)];
                if (sub >= 0) racc -= row[swz(sub)];
            }
            keep1[si * 8 + d] = racc;
        }
    }
    __syncthreads();

    // ---- phase B: s2 + epilogue ----
    vert(s2 + pbase);
    __syncthreads();
    #pragma unroll
    for (int si = 0; si < NS; ++si) {
        int s = si * 512 + t;
        int rr = s >> 6, j0 = (s & 63) << 3;
        int i = i0 + rr;
        int ch = min(i + R, HH - 1) - max(i - R, 0) + 1;
        const float* row = &lbuf[rr * PADW];
        size_t rowbase = pbase + (size_t)i * WW + j0;

        float e1v[8], e2v[8];
        {
            float4 a0 = ((const float4*)(e1 + rowbase))[0];
            float4 a1q = ((const float4*)(e1 + rowbase))[1];
            e1v[0]=a0.x; e1v[1]=a0.y; e1v[2]=a0.z; e1v[3]=a0.w;
            e1v[4]=a1q.x; e1v[5]=a1q.y; e1v[6]=a1q.z; e1v[7]=a1q.w;
        }
        if (EPI == 2) {
            float4 b0 = ((const float4*)(e2 + rowbase))[0];
            float4 b1q = ((const float4*)(e2 + rowbase))[1];
            e2v[0]=b0.x; e2v[1]=b0.y; e2v[2]=b0.z; e2v[3]=b0.w;
            e2v[4]=b1q.x; e2v[5]=b1q.y; e2v[6]=b1q.z; e2v[7]=b1q.w;
        }

        int lo = max(j0 - R, 0), hi = min(j0 + R, WW - 1);
        float racc2 = 0.f;
        for (int jj = lo; jj <= hi; ++jj) racc2 += row[swz(jj)];
        float ov[8];
        #pragma unroll
        for (int d = 0; d < 8; ++d) {
            if (d > 0) {
                int add = j0 + d + R, sub = j0 + d - R - 1;
                if (add < WW) racc2 += row[swz(add)];
                if (sub >= 0) racc2 -= row[swz(sub)];
            }
            int j = j0 + d;
            int cw = min(j + R, WW - 1) - max(j - R, 0) + 1;
            float chcw = (float)(ch * cw);
            float r1 = keep1[si * 8 + d];
            float den = fabsf(r1 - racc2) + 1e-4f * chcw;
            if (EPI == 1) {
                ov[d] = (fabsf(e1v[d]) * chcw - racc2) / den;
            } else {
                ov[d] = ((e1v[d] * chcw - racc2) / den + 0.01f) * e2v[d];
            }
        }
        float4* d4 = (float4*)&dst[rowbase];
        d4[0] = make_float4(ov[0], ov[1], ov[2], ov[3]);
        d4[1] = make_float4(ov[4], ov[5], ov[6], ov[7]);
    }
}

// ---------------- final: dual avg + map + paired reduction, 512 thr ----------------
// Block handles planes (pR, pR+16) for one tile; computes mapR, mapL in regs,
// accumulates sum mapR*exp(-10*(mapR+mapL)), atomicAdd(out, blocksum*scale).
template <int R, int TH>
__global__ __launch_bounds__(512, 8) void davg_final(const float* __restrict__ s1,
                                                     const float* __restrict__ s2,
                                                     const float* __restrict__ e1,
                                                     const float* __restrict__ e2,
                                                     float* __restrict__ out, float scale) {
    constexpr int TILES = HH / TH;
    constexpr int NS = (TH * 64) / 512;
    __shared__ float lbuf[TH * PADW];
    __shared__ float red[8];
    const int pairidx = blockIdx.x / TILES;
    const int tile    = blockIdx.x % TILES;
    const int i0      = tile * TH;
    const int planeR  = pairidx + ((pairidx >> 4) << 4);   // 0..15->0..15; 16..31->32..47
    const int t = threadIdx.x;
    const int ca = swz(t);

    float mapR[NS * 8];
    float acc = 0.f;

    #pragma unroll
    for (int half = 0; half < 2; ++half) {
        const size_t pbase = (size_t)(planeR + half * 16) * SS;

        auto vert = [&](const float* sp) {
            auto ld = [&](int gi) -> float {
                return ((unsigned)gi < (unsigned)HH) ? sp[(size_t)gi * WW + t] : 0.f;
            };
            float a = 0.f;
            #pragma unroll
            for (int k = -R; k <= R; ++k) a += ld(i0 + k);
            lbuf[ca] = a;
            #pragma unroll
            for (int oi = 1; oi < TH; ++oi) {
                a += ld(i0 + oi + R) - ld(i0 + oi - R - 1);
                lbuf[oi * PADW + ca] = a;
            }
        };

        float keep1[NS * 8];

        // phase A: s1 (max7)
        vert(s1 + pbase);
        __syncthreads();
        #pragma unroll
        for (int si = 0; si < NS; ++si) {
            int s = si * 512 + t;
            int rr = s >> 6, j0 = (s & 63) << 3;
            const float* row = &lbuf[rr * PADW];
            int lo = max(j0 - R, 0), hi = min(j0 + R, WW - 1);
            float racc = 0.f;
            for (int jj = lo; jj <= hi; ++jj) racc += row[swz(jj)];
            #pragma unroll
            for (int d = 0; d < 8; ++d) {
                if (d > 0) {
                    int add = j0 + d + R, sub = j0 + d - R - 1;
                    if (add < WW) racc += row[swz(add)];
                    if (sub >= 0) racc -= row[swz(sub)];
                }
                keep1[si * 8 + d] = racc;
            }
        }
        __syncthreads();

        // phase B: s2 (min7) + map epilogue
        vert(s2 + pbase);
        __syncthreads();
        #pragma unroll
        for (int si = 0; si < NS; ++si) {
            int s = si * 512 + t;
            int rr = s >> 6, j0 = (s & 63) << 3;
            int i = i0 + rr;
            int ch = min(i + R, HH - 1) - max(i - R, 0) + 1;
            const float* row = &lbuf[rr * PADW];
            size_t rowbase = pbase + (size_t)i * WW + j0;

            float e1v[8], e2v[8];
            {
                float4 a0 = ((const float4*)(e1 + rowbase))[0];
                float4 a1q = ((const float4*)(e1 + rowbase))[1];
                e1v[0]=a0.x; e1v[1]=a0.y; e1v[2]=a0.z; e1v[3]=a0.w;
                e1v[4]=a1q.x; e1v[5]=a1q.y; e1v[6]=a1q.z; e1v[7]=a1q.w;
                float4 b0 = ((const float4*)(e2 + rowbase))[0];
                float4 b1q = ((const float4*)(e2 + rowbase))[1];
                e2v[0]=b0.x; e2v[1]=b0.y; e2v[2]=b0.z; e2v[3]=b0.w;
                e2v[4]=b1q.x; e2v[5]=b1q.y; e2v[6]=b1q.z; e2v[7]=b1q.w;
            }

            int lo = max(j0 - R, 0), hi = min(j0 + R, WW - 1);
            float racc2 = 0.f;
            for (int jj = lo; jj <= hi; ++jj) racc2 += row[swz(jj)];
            #pragma unroll
            for (int d = 0; d < 8; ++d) {
                if (d > 0) {
                    int add = j0 + d + R, sub = j0 + d - R - 1;
                    if (add < WW) racc2 += row[swz(add)];
                    if (sub >= 0) racc2 -= row[swz(sub)];
                }
                int j = j0 + d;
                int cw = min(j + R, WW - 1) - max(j - R, 0) + 1;
                float chcw = (float)(ch * cw);
                float r1 = keep1[si * 8 + d];
                float den = fabsf(r1 - racc2) + 1e-4f * chcw;
                float mp = ((e1v[d] * chcw - racc2) / den + 0.01f) * e2v[d];
                if (half == 0) {
                    mapR[si * 8 + d] = mp;
                } else {
                    float mr = mapR[si * 8 + d];
                    acc += mr * expf(-10.f * (mr + mp));
                }
            }
        }
        __syncthreads();                           // before lbuf reuse
    }

    #pragma unroll
    for (int off = 32; off; off >>= 1) acc += __shfl_down(acc, off);
    int lane = t & 63, wv = t >> 6;
    if (lane == 0) red[wv] = acc;
    __syncthreads();
    if (t == 0) {
        float v = 0.f;
        #pragma unroll
        for (int k = 0; k < 8; ++k) v += red[k];
        atomicAdd(out, v * scale);
    }
}

// ---------------- host orchestration ----------------
// Workspace budget is 4 stacks of 64 planes (256 MiB) — verified available.
// Buffer recycling: G=g -> dual9(G->A,B) -> davg8(A,B,G->C) -> avg_abs(G->A=go)
// -> dual7(A->B=max7, G=min7) -> final(B,G,A,C -> atomicAdd out).

extern "C" void kernel_launch(void* const* d_in, const int* in_sizes, int n_in,
                              void* d_out, int out_size, void* d_ws, size_t ws_size,
                              hipStream_t stream) {
    const float* Rrgb = (const float*)d_in[0];
    const float* Lrgb = (const float*)d_in[1];
    float* out = (float*)d_out;
    float* w = (float*)d_ws;
    const float scale = 1.f / (float)P16N;
    const int gradblk = (P16N / 4 + 255) / 256;

    hipMemsetAsync(out, 0, sizeof(float) * (size_t)out_size, stream);

    const size_t stack64 = (size_t)64 * SS;
    const size_t stack32 = (size_t)32 * SS;

    if (ws_size >= 4 * stack64 * sizeof(float)) {
        // single pass: 4 buffers of 64 planes [0..16)=Rgx [16..32)=Lgx [32..48)=Rgy [48..64)=Lgy
        float* G = w;
        float* A = G + stack64;
        float* B = A + stack64;
        float* C = B + stack64;
        grad_both<<<gradblk, 256, 0, stream>>>(Rrgb, G, 0, 32, 2);
        grad_both<<<gradblk, 256, 0, stream>>>(Lrgb, G, 16, 48, 2);
        int gp = 64 * (HH / 16);
        dual_pool<true, 4, 16><<<gp, 512, 0, stream>>>(G, A, B);          // A=max9|g|, B=min9|g|
        davg_pool<8, 1, 16><<<gp, 512, 0, stream>>>(A, B, G, nullptr, C); // C=gn1
        avg_abs_pool<2, 16><<<gp, 512, 0, stream>>>(G, A);                // A=go (G dead)
        dual_pool<false, 3, 16><<<gp, 512, 0, stream>>>(A, B, G);         // B=max7, G=min7
        int fp = 32 * (HH / 16);
        davg_final<3, 16><<<fp, 512, 0, stream>>>(B, G, A, C, out, scale);
    } else {
        // two passes: 4 buffers of 32 planes (128 MiB), one direction at a time
        float* G = w;
        float* A = G + stack32;
        float* B = A + stack32;
        float* C = B + stack32;
        for (int dir = 0; dir < 2; ++dir) {
            grad_both<<<gradblk, 256, 0, stream>>>(Rrgb, G, 0, 0, dir);
            grad_both<<<gradblk, 256, 0, stream>>>(Lrgb, G, 16, 16, dir);
            int gp = 32 * (HH / 16);
            dual_pool<true, 4, 16><<<gp, 512, 0, stream>>>(G, A, B);
            davg_pool<8, 1, 16><<<gp, 512, 0, stream>>>(A, B, G, nullptr, C);
            avg_abs_pool<2, 16><<<gp, 512, 0, stream>>>(G, A);
            dual_pool<false, 3, 16><<<gp, 512, 0, stream>>>(A, B, G);
            int fp = 16 * (HH / 16);
            davg_final<3, 16><<<fp, 512, 0, stream>>>(B, G, A, C, out, scale);
        }
    }
}

// Round 5
// 478.288 us; speedup vs baseline: 1.0557x; 1.0436x over previous
//
#include <hip/hip_runtime.h>

#define HH 512
#define WW 512
#define SS (HH * WW)          // elements per plane (2^18)
#define P16N (16 * SS)        // 16 planes (2^22)
#define PADW 576              // skewed LDS row: addr(j) = j + (j>>3)

constexpr float FINF = 3.402823466e38f;

__device__ __forceinline__ int swz(int j) { return j + (j >> 3); }

// XCD-aware chunked swizzle (requires nwg % 8 == 0; all grids here comply).
__device__ __forceinline__ int xcd_swz(int bid, int nwg) {
    int cpx = nwg >> 3;
    return (bid & 7) * cpx + (bid >> 3);
}

__device__ __forceinline__ float gray1(float r, float g, float b) {
    return 0.299f * r + 0.587f * g + 0.114f * b;
}

// inverse of small integer c in [R+1, 2R+1] without v_div (cmp+cndmask chain)
template <int R>
__device__ __forceinline__ float invsmall(int c) {
    float r = 1.f / (float)(2 * R + 1);
    #pragma unroll
    for (int v = R + 1; v < 2 * R + 1; ++v)
        if (c == v) r = 1.f / (float)v;      // compile-time constants
    return r;
}

// ---------------- grad (gray fused, both dirs, 4 px/thread) ----------------
__global__ __launch_bounds__(256) void grad_both(const float* __restrict__ rgb,
                                                 float* __restrict__ dst,
                                                 int gxp0, int gyp0, int dirsel) {
    int sp = blockIdx.x * 256 + threadIdx.x;
    int idx = sp << 2;                             // [0, P16N)
    int img = idx >> 18;
    int pix = idx & (SS - 1);
    int i = pix >> 9, j0 = pix & (WW - 1);
    const float* p0 = rgb + (size_t)img * 3 * SS + pix;

    float4 r = *(const float4*)p0;
    float4 g = *(const float4*)(p0 + SS);
    float4 b = *(const float4*)(p0 + 2 * SS);
    float4 gy4 = make_float4(gray1(r.x, g.x, b.x), gray1(r.y, g.y, b.y),
                             gray1(r.z, g.z, b.z), gray1(r.w, g.w, b.w));
    if (dirsel != 1) {
        float grs = 0.f;
        if (j0 + 4 < WW) grs = gray1(p0[4], p0[SS + 4], p0[2 * SS + 4]);
        float4 gx = make_float4(gy4.x - gy4.y, gy4.y - gy4.z, gy4.z - gy4.w, gy4.w - grs);
        *(float4*)(dst + (size_t)(gxp0 + img) * SS + pix) = gx;
    }
    if (dirsel != 0) {
        float4 gd = make_float4(0.f, 0.f, 0.f, 0.f);
        if (i < HH - 1) {
            float4 r2 = *(const float4*)(p0 + WW);
            float4 g2 = *(const float4*)(p0 + SS + WW);
            float4 b2 = *(const float4*)(p0 + 2 * SS + WW);
            gd = make_float4(gray1(r2.x, g2.x, b2.x), gray1(r2.y, g2.y, b2.y),
                             gray1(r2.z, g2.z, b2.z), gray1(r2.w, g2.w, b2.w));
        }
        float4 gy = make_float4(gy4.x - gd.x, gy4.y - gd.y, gy4.z - gd.z, gy4.w - gd.w);
        *(float4*)(dst + (size_t)(gyp0 + img) * SS + pix) = gy;
    }
}

// ---------------- dual max+min pool (column-first, skewed LDS) ----------------
// 256 thr, float2 per thread. Single ring buffer rb[W]; out-of-range / stale
// rows excluded by EXACT wrap-counted validity mask (all compile-time).
// Vertical max -> LDS, vertical min -> regs; horizontal max -> dmax; reload;
// horizontal min -> dmin. LDS 36864 B -> 4 blocks/CU.
template <bool PREABS, int R, int TH>
__global__ __launch_bounds__(256, 4) void dual_pool(const float* __restrict__ src,
                                                    float* __restrict__ dmax,
                                                    float* __restrict__ dmin) {
    constexpr int TILES = HH / TH;
    constexpr int W = 2 * R + 1;
    constexpr int NS = (TH * 64) / 256;
    __shared__ float lbuf[TH * PADW];

    const int wg    = xcd_swz(blockIdx.x, gridDim.x);
    const int plane = wg / TILES;
    const int tile  = wg % TILES;
    const int i0    = tile * TH;
    const size_t pbase = (size_t)plane * SS;
    const float* sp = src + pbase;
    const int t = threadIdx.x;
    const int ca = swz(2 * t);                     // ca+1 == swz(2t+1)

    float2 rb[W];
    float2 keepmn[TH];
    auto ld = [&](int gi) -> float2 {
        float2 u = ((const float2*)(sp + (size_t)gi * WW))[t];
        if (PREABS) { u.x = fabsf(u.x); u.y = fabsf(u.y); }
        return u;
    };
    #pragma unroll
    for (int k = 0; k < W; ++k)
        if ((unsigned)(i0 - R + k) < (unsigned)HH) rb[k] = ld(i0 - R + k);
    #pragma unroll
    for (int oi = 0; oi < TH; ++oi) {
        if (oi > 0) {
            if ((unsigned)(i0 + oi + R) < (unsigned)HH) rb[(oi - 1) % W] = ld(i0 + oi + R);
        }
        float2 mx = make_float2(-FINF, -FINF), mn = make_float2(FINF, FINF);
        #pragma unroll
        for (int k = 0; k < W; ++k) {
            int wrap = (oi > k) ? ((oi - 1 - k) / W + 1) : 0;   // compile-time
            int ro = k - R + wrap * W;                          // exact row in slot k
            if ((unsigned)(i0 + ro) < (unsigned)HH) {           // block-uniform
                mx.x = fmaxf(mx.x, rb[k].x); mx.y = fmaxf(mx.y, rb[k].y);
                mn.x = fminf(mn.x, rb[k].x); mn.y = fminf(mn.y, rb[k].y);
            }
        }
        lbuf[oi * PADW + ca] = mx.x; lbuf[oi * PADW + ca + 1] = mx.y;
        keepmn[oi] = mn;
    }
    __syncthreads();

    // horizontal max -> dmax
    #pragma unroll
    for (int si = 0; si < NS; ++si) {
        int s = si * 256 + t;
        int rr = s >> 6, j0 = (s & 63) << 3;
        const float* rx = &lbuf[rr * PADW];
        float vx[2 * R + 8];
        #pragma unroll
        for (int k = 0; k < 2 * R + 8; ++k) {
            int jj = j0 - R + k;
            bool ok = (unsigned)jj < (unsigned)WW;
            int jc = swz(min(max(jj, 0), WW - 1));
            vx[k] = ok ? rx[jc] : -FINF;
        }
        float ox[8];
        #pragma unroll
        for (int d = 0; d < 8; ++d) {
            float mx = vx[d];
            #pragma unroll
            for (int k = 1; k <= 2 * R; ++k) mx = fmaxf(mx, vx[d + k]);
            ox[d] = mx;
        }
        size_t o = pbase + (size_t)(i0 + rr) * WW + j0;
        ((float4*)&dmax[o])[0] = make_float4(ox[0], ox[1], ox[2], ox[3]);
        ((float4*)&dmax[o])[1] = make_float4(ox[4], ox[5], ox[6], ox[7]);
    }
    __syncthreads();

    #pragma unroll
    for (int oi = 0; oi < TH; ++oi) {
        lbuf[oi * PADW + ca] = keepmn[oi].x;
        lbuf[oi * PADW + ca + 1] = keepmn[oi].y;
    }
    __syncthreads();

    // horizontal min -> dmin
    #pragma unroll
    for (int si = 0; si < NS; ++si) {
        int s = si * 256 + t;
        int rr = s >> 6, j0 = (s & 63) << 3;
        const float* rn = &lbuf[rr * PADW];
        float vn[2 * R + 8];
        #pragma unroll
        for (int k = 0; k < 2 * R + 8; ++k) {
            int jj = j0 - R + k;
            bool ok = (unsigned)jj < (unsigned)WW;
            int jc = swz(min(max(jj, 0), WW - 1));
            vn[k] = ok ? rn[jc] : FINF;
        }
        float on[8];
        #pragma unroll
        for (int d = 0; d < 8; ++d) {
            float mn = vn[d];
            #pragma unroll
            for (int k = 1; k <= 2 * R; ++k) mn = fminf(mn, vn[d + k]);
            on[d] = mn;
        }
        size_t o = pbase + (size_t)(i0 + rr) * WW + j0;
        ((float4*)&dmin[o])[0] = make_float4(on[0], on[1], on[2], on[3]);
        ((float4*)&dmin[o])[1] = make_float4(on[4], on[5], on[6], on[7]);
    }
}

// ---------------- single avg pool (abs output), division-free ----------------
template <int R, int TH>
__global__ __launch_bounds__(256, 4) void avg_abs_pool(const float* __restrict__ src,
                                                       float* __restrict__ dst) {
    constexpr int TILES = HH / TH;
    __shared__ float ls[TH * PADW];
    const int wg    = xcd_swz(blockIdx.x, gridDim.x);
    const int plane = wg / TILES;
    const int tile  = wg % TILES;
    const int i0    = tile * TH;
    const size_t pbase = (size_t)plane * SS;
    const float* sp = src + pbase;
    const int t = threadIdx.x;

    auto ld = [&](int gi) -> float2 {
        if ((unsigned)gi < (unsigned)HH) return ((const float2*)(sp + (size_t)gi * WW))[t];
        return make_float2(0.f, 0.f);
    };
    float2 acc = make_float2(0.f, 0.f);
    #pragma unroll
    for (int k = -R; k <= R; ++k) { float2 v = ld(i0 + k); acc.x += v.x; acc.y += v.y; }
    const int ca = swz(2 * t);
    ls[ca] = acc.x; ls[ca + 1] = acc.y;
    #pragma unroll
    for (int oi = 1; oi < TH; ++oi) {
        float2 a = ld(i0 + oi + R), s = ld(i0 + oi - R - 1);
        acc.x += a.x - s.x; acc.y += a.y - s.y;
        ls[oi * PADW + ca] = acc.x; ls[oi * PADW + ca + 1] = acc.y;
    }
    __syncthreads();

    for (int s = t; s < TH * 64; s += 256) {
        int rr = s >> 6, j0 = (s & 63) << 3;
        int i = i0 + rr;
        int ch = min(i + R, HH - 1) - max(i - R, 0) + 1;
        float invch = invsmall<R>(ch);
        const float* row = &ls[rr * PADW];
        int lo = max(j0 - R, 0), hi = min(j0 + R, WW - 1);
        float racc = 0.f;
        for (int jj = lo; jj <= hi; ++jj) racc += row[swz(jj)];
        float ov[8];
        #pragma unroll
        for (int d = 0; d < 8; ++d) {
            if (d > 0) {
                int add = j0 + d + R, sub = j0 + d - R - 1;
                if (add < WW) racc += row[swz(add)];
                if (sub >= 0) racc -= row[swz(sub)];
            }
            int j = j0 + d;
            int cw = min(j + R, WW - 1) - max(j - R, 0) + 1;
            ov[d] = fabsf(racc * (invch * invsmall<R>(cw)));
        }
        float4* d4 = (float4*)&dst[pbase + (size_t)i * WW + j0];
        d4[0] = make_float4(ov[0], ov[1], ov[2], ov[3]);
        d4[1] = make_float4(ov[4], ov[5], ov[6], ov[7]);
    }
}

// ---------------- dual-input avg pool + gn1 epilogue (EPI=1) ----------------
// out = (|e1|*chcw - racc2)/(|racc1 - racc2| + 1e-4*chcw)    [division-free]
// Phase-split over ONE LDS buffer: s1 horizontal sums held in regs (keep1).
template <int R, int EPI, int TH>
__global__ __launch_bounds__(256, 4) void davg_pool(const float* __restrict__ s1,
                                                    const float* __restrict__ s2,
                                                    const float* __restrict__ e1,
                                                    const float* __restrict__ e2,
                                                    float* __restrict__ dst) {
    constexpr int TILES = HH / TH;
    constexpr int NS = (TH * 64) / 256;
    __shared__ float lbuf[TH * PADW];
    const int wg    = xcd_swz(blockIdx.x, gridDim.x);
    const int plane = wg / TILES;
    const int tile  = wg % TILES;
    const int i0    = tile * TH;
    const size_t pbase = (size_t)plane * SS;
    const int t = threadIdx.x;
    const int ca = swz(2 * t);

    auto vert = [&](const float* sp) {
        auto ld = [&](int gi) -> float2 {
            if ((unsigned)gi < (unsigned)HH) return ((const float2*)(sp + (size_t)gi * WW))[t];
            return make_float2(0.f, 0.f);
        };
        float2 acc = make_float2(0.f, 0.f);
        #pragma unroll
        for (int k = -R; k <= R; ++k) { float2 v = ld(i0 + k); acc.x += v.x; acc.y += v.y; }
        lbuf[ca] = acc.x; lbuf[ca + 1] = acc.y;
        #pragma unroll
        for (int oi = 1; oi < TH; ++oi) {
            float2 a = ld(i0 + oi + R), s = ld(i0 + oi - R - 1);
            acc.x += a.x - s.x; acc.y += a.y - s.y;
            lbuf[oi * PADW + ca] = acc.x; lbuf[oi * PADW + ca + 1] = acc.y;
        }
    };

    float keep1[NS * 8];                           // raw horizontal sums of s1

    // ---- phase A: s1 ----
    vert(s1 + pbase);
    __syncthreads();
    #pragma unroll
    for (int si = 0; si < NS; ++si) {
        int s = si * 256 + t;
        int rr = s >> 6, j0 = (s & 63) << 3;
        const float* row = &lbuf[rr * PADW];
        int lo = max(j0 - R, 0), hi = min(j0 + R, WW - 1);
        float racc = 0.f;
        for (int jj = lo; jj <= hi; ++jj) racc += row[swz(jj)];
        #pragma unroll
        for (int d = 0; d < 8; ++d) {
            if (d > 0) {
                int add = j0 + d + R, sub = j0 + d - R - 1;
                if (add < WW) racc += row[swz(add)];
                if (sub >= 0) racc -= row[swz(sub)];
            }
            keep1[si * 8 + d] = racc;
        }
    }
    __syncthreads();

    // ---- phase B: s2 + epilogue ----
    vert(s2 + pbase);
    __syncthreads();
    #pragma unroll
    for (int si = 0; si < NS; ++si) {
        int s = si * 256 + t;
        int rr = s >> 6, j0 = (s & 63) << 3;
        int i = i0 + rr;
        int ch = min(i + R, HH - 1) - max(i - R, 0) + 1;
        const float* row = &lbuf[rr * PADW];
        size_t rowbase = pbase + (size_t)i * WW + j0;

        float e1v[8], e2v[8];
        {
            float4 a0 = ((const float4*)(e1 + rowbase))[0];
            float4 a1q = ((const float4*)(e1 + rowbase))[1];
            e1v[0]=a0.x; e1v[1]=a0.y; e1v[2]=a0.z; e1v[3]=a0.w;
            e1v[4]=a1q.x; e1v[5]=a1q.y; e1v[6]=a1q.z; e1v[7]=a1q.w;
        }
        if (EPI == 2) {
            float4 b0 = ((const float4*)(e2 + rowbase))[0];
            float4 b1q = ((const float4*)(e2 + rowbase))[1];
            e2v[0]=b0.x; e2v[1]=b0.y; e2v[2]=b0.z; e2v[3]=b0.w;
            e2v[4]=b1q.x; e2v[5]=b1q.y; e2v[6]=b1q.z; e2v[7]=b1q.w;
        }

        int lo = max(j0 - R, 0), hi = min(j0 + R, WW - 1);
        float racc2 = 0.f;
        for (int jj = lo; jj <= hi; ++jj) racc2 += row[swz(jj)];
        float ov[8];
        #pragma unroll
        for (int d = 0; d < 8; ++d) {
            if (d > 0) {
                int add = j0 + d + R, sub = j0 + d - R - 1;
                if (add < WW) racc2 += row[swz(add)];
                if (sub >= 0) racc2 -= row[swz(sub)];
            }
            int j = j0 + d;
            int cw = min(j + R, WW - 1) - max(j - R, 0) + 1;
            float chcw = (float)(ch * cw);
            float r1 = keep1[si * 8 + d];
            float den = fabsf(r1 - racc2) + 1e-4f * chcw;
            if (EPI == 1) {
                ov[d] = (fabsf(e1v[d]) * chcw - racc2) / den;
            } else {
                ov[d] = ((e1v[d] * chcw - racc2) / den + 0.01f) * e2v[d];
            }
        }
        float4* d4 = (float4*)&dst[rowbase];
        d4[0] = make_float4(ov[0], ov[1], ov[2], ov[3]);
        d4[1] = make_float4(ov[4], ov[5], ov[6], ov[7]);
    }
}

// ---------------- final: dual avg + map + paired reduction ----------------
// Block handles planes (pR, pR+16) for one tile; computes mapR, mapL in regs,
// accumulates sum mapR*exp(-10*(mapR+mapL)), atomicAdd(out, blocksum*scale).
template <int R, int TH>
__global__ __launch_bounds__(256, 4) void davg_final(const float* __restrict__ s1,
                                                     const float* __restrict__ s2,
                                                     const float* __restrict__ e1,
                                                     const float* __restrict__ e2,
                                                     float* __restrict__ out, float scale) {
    constexpr int TILES = HH / TH;
    constexpr int NS = (TH * 64) / 256;
    __shared__ float lbuf[TH * PADW];
    __shared__ float red[4];
    const int wg      = xcd_swz(blockIdx.x, gridDim.x);
    const int pairidx = wg / TILES;
    const int tile    = wg % TILES;
    const int i0      = tile * TH;
    const int planeR  = pairidx + ((pairidx >> 4) << 4);   // 0..15->0..15; 16..31->32..47
    const int t = threadIdx.x;
    const int ca = swz(2 * t);

    float mapR[NS * 8];
    float acc = 0.f;

    #pragma unroll
    for (int half = 0; half < 2; ++half) {
        const size_t pbase = (size_t)(planeR + half * 16) * SS;

        auto vert = [&](const float* sp) {
            auto ld = [&](int gi) -> float2 {
                if ((unsigned)gi < (unsigned)HH) return ((const float2*)(sp + (size_t)gi * WW))[t];
                return make_float2(0.f, 0.f);
            };
            float2 a = make_float2(0.f, 0.f);
            #pragma unroll
            for (int k = -R; k <= R; ++k) { float2 v = ld(i0 + k); a.x += v.x; a.y += v.y; }
            lbuf[ca] = a.x; lbuf[ca + 1] = a.y;
            #pragma unroll
            for (int oi = 1; oi < TH; ++oi) {
                float2 p = ld(i0 + oi + R), q = ld(i0 + oi - R - 1);
                a.x += p.x - q.x; a.y += p.y - q.y;
                lbuf[oi * PADW + ca] = a.x; lbuf[oi * PADW + ca + 1] = a.y;
            }
        };

        float keep1[NS * 8];

        // phase A: s1 (max7)
        vert(s1 + pbase);
        __syncthreads();
        #pragma unroll
        for (int si = 0; si < NS; ++si) {
            int s = si * 256 + t;
            int rr = s >> 6, j0 = (s & 63) << 3;
            const float* row = &lbuf[rr * PADW];
            int lo = max(j0 - R, 0), hi = min(j0 + R, WW - 1);
            float racc = 0.f;
            for (int jj = lo; jj <= hi; ++jj) racc += row[swz(jj)];
            #pragma unroll
            for (int d = 0; d < 8; ++d) {
                if (d > 0) {
                    int add = j0 + d + R, sub = j0 + d - R - 1;
                    if (add < WW) racc += row[swz(add)];
                    if (sub >= 0) racc -= row[swz(sub)];
                }
                keep1[si * 8 + d] = racc;
            }
        }
        __syncthreads();

        // phase B: s2 (min7) + map epilogue
        vert(s2 + pbase);
        __syncthreads();
        #pragma unroll
        for (int si = 0; si < NS; ++si) {
            int s = si * 256 + t;
            int rr = s >> 6, j0 = (s & 63) << 3;
            int i = i0 + rr;
            int ch = min(i + R, HH - 1) - max(i - R, 0) + 1;
            const float* row = &lbuf[rr * PADW];
            size_t rowbase = pbase + (size_t)i * WW + j0;

            float e1v[8], e2v[8];
            {
                float4 a0 = ((const float4*)(e1 + rowbase))[0];
                float4 a1q = ((const float4*)(e1 + rowbase))[1];
                e1v[0]=a0.x; e1v[1]=a0.y; e1v[2]=a0.z; e1v[3]=a0.w;
                e1v[4]=a1q.x; e1v[5]=a1q.y; e1v[6]=a1q.z; e1v[7]=a1q.w;
                float4 b0 = ((const float4*)(e2 + rowbase))[0];
                float4 b1q = ((const float4*)(e2 + rowbase))[1];
                e2v[0]=b0.x; e2v[1]=b0.y; e2v[2]=b0.z; e2v[3]=b0.w;
                e2v[4]=b1q.x; e2v[5]=b1q.y; e2v[6]=b1q.z; e2v[7]=b1q.w;
            }

            int lo = max(j0 - R, 0), hi = min(j0 + R, WW - 1);
            float racc2 = 0.f;
            for (int jj = lo; jj <= hi; ++jj) racc2 += row[swz(jj)];
            #pragma unroll
            for (int d = 0; d < 8; ++d) {
                if (d > 0) {
                    int add = j0 + d + R, sub = j0 + d - R - 1;
                    if (add < WW) racc2 += row[swz(add)];
                    if (sub >= 0) racc2 -= row[swz(sub)];
                }
                int j = j0 + d;
                int cw = min(j + R, WW - 1) - max(j - R, 0) + 1;
                float chcw = (float)(ch * cw);
                float r1 = keep1[si * 8 + d];
                float den = fabsf(r1 - racc2) + 1e-4f * chcw;
                float mp = ((e1v[d] * chcw - racc2) / den + 0.01f) * e2v[d];
                if (half == 0) {
                    mapR[si * 8 + d] = mp;
                } else {
                    float mr = mapR[si * 8 + d];
                    acc += mr * expf(-10.f * (mr + mp));
                }
            }
        }
        __syncthreads();                           // before lbuf reuse
    }

    #pragma unroll
    for (int off = 32; off; off >>= 1) acc += __shfl_down(acc, off);
    int lane = t & 63, wv = t >> 6;
    if (lane == 0) red[wv] = acc;
    __syncthreads();
    if (t == 0) atomicAdd(out, (red[0] + red[1] + red[2] + red[3]) * scale);
}

// ---------------- host orchestration ----------------
// 4 stacks of 64 planes (256 MiB). Buffer recycling:
// G=g -> dual9(G->A,B) -> davg8(A,B,G->C=gn1) -> avg_abs(G->A=go)
// -> dual7(A->B=max7, G=min7) -> final(B,G,A,C -> atomicAdd out).

extern "C" void kernel_launch(void* const* d_in, const int* in_sizes, int n_in,
                              void* d_out, int out_size, void* d_ws, size_t ws_size,
                              hipStream_t stream) {
    const float* Rrgb = (const float*)d_in[0];
    const float* Lrgb = (const float*)d_in[1];
    float* out = (float*)d_out;
    float* w = (float*)d_ws;
    const float scale = 1.f / (float)P16N;
    const int gradblk = (P16N / 4 + 255) / 256;

    hipMemsetAsync(out, 0, sizeof(float) * (size_t)out_size, stream);

    const size_t stack64 = (size_t)64 * SS;
    const size_t stack32 = (size_t)32 * SS;

    if (ws_size >= 4 * stack64 * sizeof(float)) {
        // single pass: 4 buffers of 64 planes [0..16)=Rgx [16..32)=Lgx [32..48)=Rgy [48..64)=Lgy
        float* G = w;
        float* A = G + stack64;
        float* B = A + stack64;
        float* C = B + stack64;
        grad_both<<<gradblk, 256, 0, stream>>>(Rrgb, G, 0, 32, 2);
        grad_both<<<gradblk, 256, 0, stream>>>(Lrgb, G, 16, 48, 2);
        int gp = 64 * (HH / 16);                                          // 2048, %8==0
        dual_pool<true, 4, 16><<<gp, 256, 0, stream>>>(G, A, B);          // A=max9|g|, B=min9|g|
        davg_pool<8, 1, 16><<<gp, 256, 0, stream>>>(A, B, G, nullptr, C); // C=gn1
        avg_abs_pool<2, 16><<<gp, 256, 0, stream>>>(G, A);                // A=go (G dead)
        dual_pool<false, 3, 16><<<gp, 256, 0, stream>>>(A, B, G);         // B=max7, G=min7
        int fp = 32 * (HH / 16);                                          // 1024, %8==0
        davg_final<3, 16><<<fp, 256, 0, stream>>>(B, G, A, C, out, scale);
    } else {
        // two passes: 4 buffers of 32 planes (128 MiB), one direction at a time
        float* G = w;
        float* A = G + stack32;
        float* B = A + stack32;
        float* C = B + stack32;
        for (int dir = 0; dir < 2; ++dir) {
            grad_both<<<gradblk, 256, 0, stream>>>(Rrgb, G, 0, 0, dir);
            grad_both<<<gradblk, 256, 0, stream>>>(Lrgb, G, 16, 16, dir);
            int gp = 32 * (HH / 16);                                      // 1024
            dual_pool<true, 4, 16><<<gp, 256, 0, stream>>>(G, A, B);
            davg_pool<8, 1, 16><<<gp, 256, 0, stream>>>(A, B, G, nullptr, C);
            avg_abs_pool<2, 16><<<gp, 256, 0, stream>>>(G, A);
            dual_pool<false, 3, 16><<<gp, 256, 0, stream>>>(A, B, G);
            int fp = 16 * (HH / 16);                                      // 512
            davg_final<3, 16><<<fp, 256, 0, stream>>>(B, G, A, C, out, scale);
        }
    }
}